// Round 9
// baseline (355.286 us; speedup 1.0000x reference)
//
#include <hip/hip_runtime.h>
#include <stdint.h>

#define BATCH 4
#define SEQL  16384
#define DIM   64
#define NST   16
#define TOK   (BATCH*SEQL)        /* 65536 tokens */
#define EL    ((size_t)TOK*DIM)   /* 4194304 elems per [B,L,D] array */
#define NCH   256                 /* chunks per (b,dir) */
#define CHL   64                  /* chunk length; NCH*CHL == SEQL */

typedef __attribute__((ext_vector_type(8))) short short8;
typedef __attribute__((ext_vector_type(4))) float f32x4;

__device__ __forceinline__ float nan2num(float x, float nv, float pv, float mv){
  if (__builtin_isnan(x)) return nv;
  if (__builtin_isinf(x)) return x > 0.f ? pv : mv;
  return x;
}
__device__ __forceinline__ float siluf(float x){ return x / (1.f + __expf(-x)); }
__device__ __forceinline__ float b2f(unsigned short s){
  union { unsigned u; float f; } v; v.u = ((unsigned)s) << 16; return v.f;
}
__device__ __forceinline__ unsigned short f2b(float f){
  union { float f; unsigned u; } v; v.f = f;
  unsigned r = v.u + 0x7fffu + ((v.u >> 16) & 1u);   // RNE
  return (unsigned short)(r >> 16);
}
__device__ __forceinline__ void b4f(uint2 v, float* o){
  o[0] = b2f((unsigned short)(v.x & 0xffff));
  o[1] = b2f((unsigned short)(v.x >> 16));
  o[2] = b2f((unsigned short)(v.y & 0xffff));
  o[3] = b2f((unsigned short)(v.y >> 16));
}
// fast softplus: ln(1+e^x) = log2(1+2^(x*log2e))*ln2  (HW v_exp/v_log, no libm)
__device__ __forceinline__ float softplus_fast(float x){
  if (x > 20.f) return x;
  float t = exp2f(x * 1.44269504f);
  return __log2f(1.f + t) * 0.69314718f;
}

// ================================================================ MEGA1
__global__ __launch_bounds__(256) void mega1(
    const float* __restrict__ in0, const float* __restrict__ in1,
    const float* __restrict__ n0w, const float* __restrict__ n0b,
    const float* __restrict__ n1w, const float* __restrict__ n1b,
    const float* __restrict__ cww, const float* __restrict__ cwb,
    const float* __restrict__ cwnw, const float* __restrict__ cwnb,
    const float* __restrict__ ipw, const float* __restrict__ ipew,
    float* __restrict__ x0n, float* __restrict__ wg,
    float* __restrict__ xa,  float* __restrict__ xe,
    unsigned short* __restrict__ zb, unsigned short* __restrict__ zeb)
{
  __shared__ __align__(16) short Wl[192*72];
  __shared__ __align__(16) short Al[128*72];
  int tid = threadIdx.x;
  int t0 = blockIdx.x * 128;
  int lane = tid & 63, wv = tid >> 6;
  int n = lane & 15, q = lane >> 4;
  f32x4 wacc[2][4];

  #pragma unroll
  for (int s = 0; s < 2; ++s){
    const float* ips = s ? ipew : ipw;
    for (int sseg = tid; sseg < 192*8; sseg += 256){
      int row = sseg >> 3, sg = sseg & 7;
      const float* src = (row < 64) ? (cww + (size_t)row*128 + s*64 + sg*8)
                                    : (ips + (size_t)(row-64)*64 + sg*8);
      float4 f0 = ((const float4*)src)[0];
      float4 f1 = ((const float4*)src)[1];
      short8 v;
      v[0]=(short)f2b(f0.x); v[1]=(short)f2b(f0.y); v[2]=(short)f2b(f0.z); v[3]=(short)f2b(f0.w);
      v[4]=(short)f2b(f1.x); v[5]=(short)f2b(f1.y); v[6]=(short)f2b(f1.z); v[7]=(short)f2b(f1.w);
      *(short8*)&Wl[row*72 + sg*8] = v;
    }
    {
      const float* inp = s ? in1 : in0;
      const float* nw  = s ? n1w : n0w;
      const float* nb  = s ? n1b : n0b;
      int tl = tid >> 2, p = tid & 3;
      float gw[16], gb[16];
      #pragma unroll
      for (int i = 0; i < 4; ++i){
        float4 w4 = ((const float4*)(nw + p*16))[i];
        float4 b4 = ((const float4*)(nb + p*16))[i];
        gw[4*i]=w4.x; gw[4*i+1]=w4.y; gw[4*i+2]=w4.z; gw[4*i+3]=w4.w;
        gb[4*i]=b4.x; gb[4*i+1]=b4.y; gb[4*i+2]=b4.z; gb[4*i+3]=b4.w;
      }
      #pragma unroll
      for (int sp = 0; sp < 2; ++sp){
        int tok_l = sp*64 + tl;
        size_t ga = ((size_t)(t0 + tok_l))*64 + p*16;
        float v[16]; float s1 = 0.f, s2 = 0.f;
        #pragma unroll
        for (int i = 0; i < 4; ++i){
          float4 f = ((const float4*)(inp + ga))[i];
          float a0 = nan2num(f.x,0.f,1.f,-1.f), a1 = nan2num(f.y,0.f,1.f,-1.f);
          float a2 = nan2num(f.z,0.f,1.f,-1.f), a3 = nan2num(f.w,0.f,1.f,-1.f);
          v[4*i]=a0; v[4*i+1]=a1; v[4*i+2]=a2; v[4*i+3]=a3;
          s1 += a0+a1+a2+a3; s2 += a0*a0+a1*a1+a2*a2+a3*a3;
        }
        s1 += __shfl_xor(s1,1,64); s1 += __shfl_xor(s1,2,64);
        s2 += __shfl_xor(s2,1,64); s2 += __shfl_xor(s2,2,64);
        float m = s1*(1.f/64.f);
        float var = s2*(1.f/64.f) - m*m;
        float rs = rsqrtf(var + 1e-5f);
        float xr[16];
        #pragma unroll
        for (int i = 0; i < 16; ++i){
          float x = nan2num((v[i]-m)*rs*gw[i] + gb[i], 0.f, 1.f, -1.f);
          xr[i] = x;
          Al[tok_l*72 + p*16 + i] = (short)f2b(x);
        }
        if (s == 0){
          #pragma unroll
          for (int i = 0; i < 4; ++i)
            ((float4*)(x0n + ga))[i] = make_float4(xr[4*i],xr[4*i+1],xr[4*i+2],xr[4*i+3]);
        }
      }
    }
    __syncthreads();
    float* outx = s ? xe : xa;
    unsigned short* outz = s ? zeb : zb;
    #pragma unroll
    for (int mi = 0; mi < 2; ++mi){
      int mt = wv*2 + mi;
      short8 a0 = *(const short8*)&Al[(mt*16 + n)*72 + q*8];
      short8 a1 = *(const short8*)&Al[(mt*16 + n)*72 + 32 + q*8];
      #pragma unroll
      for (int o = 0; o < 12; ++o){
        short8 b0 = *(const short8*)&Wl[(o*16 + n)*72 + q*8];
        short8 b1 = *(const short8*)&Wl[(o*16 + n)*72 + 32 + q*8];
        f32x4 c = {0.f, 0.f, 0.f, 0.f};
        c = __builtin_amdgcn_mfma_f32_16x16x32_bf16(a0, b0, c, 0, 0, 0);
        c = __builtin_amdgcn_mfma_f32_16x16x32_bf16(a1, b1, c, 0, 0, 0);
        if (o < 4){
          if (s == 0) wacc[mi][o] = c; else wacc[mi][o] += c;
        } else if (o < 8){
          #pragma unroll
          for (int r = 0; r < 4; ++r)
            outx[((size_t)(t0 + mt*16 + q*4 + r))*64 + (o-4)*16 + n] = c[r];
        } else {
          #pragma unroll
          for (int r = 0; r < 4; ++r)
            outz[((size_t)(t0 + mt*16 + q*4 + r))*64 + (o-8)*16 + n] = f2b(c[r]);
        }
      }
    }
    if (s == 0) __syncthreads();
  }
  float cb_l[4], gnw[4], gnb[4];
  #pragma unroll
  for (int o = 0; o < 4; ++o){
    cb_l[o] = cwb[o*16+n]; gnw[o] = cwnw[o*16+n]; gnb[o] = cwnb[o*16+n];
  }
  #pragma unroll
  for (int mi = 0; mi < 2; ++mi){
    #pragma unroll
    for (int r = 0; r < 4; ++r){
      float v[4]; float sv = 0.f, sq = 0.f;
      #pragma unroll
      for (int o = 0; o < 4; ++o){
        v[o] = wacc[mi][o][r] + cb_l[o];
        sv += v[o]; sq += v[o]*v[o];
      }
      sv += __shfl_xor(sv,1,64); sv += __shfl_xor(sv,2,64);
      sv += __shfl_xor(sv,4,64); sv += __shfl_xor(sv,8,64);
      sq += __shfl_xor(sq,1,64); sq += __shfl_xor(sq,2,64);
      sq += __shfl_xor(sq,4,64); sq += __shfl_xor(sq,8,64);
      float m = sv*(1.f/64.f);
      float var = sq*(1.f/64.f) - m*m;
      float rs = rsqrtf(var + 1e-5f);
      size_t tok = (size_t)t0 + (wv*2+mi)*16 + q*4 + r;
      #pragma unroll
      for (int o = 0; o < 4; ++o){
        float wn = (v[o]-m)*rs*gnw[o] + gnb[o];
        wn = nan2num(wn, 0.5f, 1.f, 0.f);
        wn = 1.f/(1.f + __expf(-wn));
        wn = fminf(fmaxf(wn, 0.01f), 0.99f);
        wg[tok*64 + o*16 + n] = wn;
      }
    }
  }
}

// ================================================================ G2: conv + xproj
// B/C stored bf16 (they are bf16-input-limited anyway).
__global__ __launch_bounds__(256) void g2_convproj(
    const float* __restrict__ xa, const float* __restrict__ xe,
    const float* __restrict__ cwf, const float* __restrict__ cbf,
    const float* __restrict__ cwr, const float* __restrict__ cbr,
    const float* __restrict__ xpwf, const float* __restrict__ xpwr,
    float* __restrict__ uf, float* __restrict__ ur,
    float* __restrict__ dltf, float* __restrict__ dltr,
    unsigned short* __restrict__ Bf, unsigned short* __restrict__ Cf,
    unsigned short* __restrict__ Br, unsigned short* __restrict__ Cr)
{
  __shared__ __align__(16) short Wl[2*48*72];
  __shared__ __align__(16) short Al[2*128*72];
  int tid = threadIdx.x;
  int b = blockIdx.x >> 7, l0 = (blockIdx.x & 127) * 128;
  size_t base = (size_t)b * SEQL;
  for (int sseg = tid; sseg < 2*48*8; sseg += 256){
    int s = sseg >= 48*8;
    int rs = sseg - s*48*8;
    int row = rs >> 3, sg = rs & 7;
    const float* xp = s ? xpwr : xpwf;
    short8 v = {0,0,0,0,0,0,0,0};
    int srcrow = (row < 32) ? (4+row) : (row < 36) ? (row-32) : -1;
    if (srcrow >= 0){
      const float* src = xp + (size_t)srcrow*64 + sg*8;
      float4 f0 = ((const float4*)src)[0];
      float4 f1 = ((const float4*)src)[1];
      v[0]=(short)f2b(f0.x); v[1]=(short)f2b(f0.y); v[2]=(short)f2b(f0.z); v[3]=(short)f2b(f0.w);
      v[4]=(short)f2b(f1.x); v[5]=(short)f2b(f1.y); v[6]=(short)f2b(f1.z); v[7]=(short)f2b(f1.w);
    }
    *(short8*)&Wl[(s*48+row)*72 + sg*8] = v;
  }
  {
    int d = tid & 63, lq = tid >> 6;
    float4 wf4 = ((const float4*)cwf)[d];
    float4 wr4 = ((const float4*)cwr)[d];
    float bf = cbf[d], brr = cbr[d];
    for (int i = 0; i < 8; ++i){
      int ll = i*16 + lq*4;
      int gl = l0 + ll;
      float rv[7], sv[7];
      #pragma unroll
      for (int j = 0; j < 7; ++j){
        int li = gl - 3 + j;
        rv[j] = (li >= 0) ? xa[(base + li)*64 + d] : 0.f;
        int lj = gl + j;
        sv[j] = (lj < SEQL) ? xe[(base + lj)*64 + d] : 0.f;
      }
      #pragma unroll
      for (int k = 0; k < 4; ++k){
        float a = bf + wf4.x*rv[k] + wf4.y*rv[k+1] + wf4.z*rv[k+2] + wf4.w*rv[k+3];
        a = siluf(a);
        uf[(base + gl + k)*64 + d] = a;
        Al[(ll+k)*72 + d] = (short)f2b(a);
        float r = brr + wr4.w*sv[k] + wr4.z*sv[k+1] + wr4.y*sv[k+2] + wr4.x*sv[k+3];
        r = siluf(r);
        ur[(base + gl + k)*64 + d] = r;
        Al[(128 + ll + k)*72 + d] = (short)f2b(r);
      }
    }
  }
  __syncthreads();
  int lane = tid & 63, wv = tid >> 6;
  int n = lane & 15, q = lane >> 4;
  #pragma unroll
  for (int s = 0; s < 2; ++s){
    const short* As = &Al[s*128*72];
    const short* Ws = &Wl[s*48*72];
    unsigned short* Bo = s ? Br : Bf;
    unsigned short* Co = s ? Cr : Cf;
    float* Do = s ? dltr : dltf;
    #pragma unroll
    for (int mi = 0; mi < 2; ++mi){
      int mt = wv*2 + mi;
      short8 a0 = *(const short8*)&As[(mt*16 + n)*72 + q*8];
      short8 a1 = *(const short8*)&As[(mt*16 + n)*72 + 32 + q*8];
      f32x4 acc[3];
      #pragma unroll
      for (int o = 0; o < 3; ++o){
        short8 b0 = *(const short8*)&Ws[(o*16 + n)*72 + q*8];
        short8 b1 = *(const short8*)&Ws[(o*16 + n)*72 + 32 + q*8];
        f32x4 c = {0.f, 0.f, 0.f, 0.f};
        c = __builtin_amdgcn_mfma_f32_16x16x32_bf16(a0, b0, c, 0, 0, 0);
        c = __builtin_amdgcn_mfma_f32_16x16x32_bf16(a1, b1, c, 0, 0, 0);
        acc[o] = c;
      }
      #pragma unroll
      for (int r = 0; r < 4; ++r){
        size_t tok = base + l0 + mt*16 + q*4 + r;
        Bo[tok*16 + n] = f2b(acc[0][r]);
        Co[tok*16 + n] = f2b(acc[1][r]);
        if (n < 4) Do[tok*4 + n] = acc[2][r];
      }
    }
  }
}

// ================================================================ K4a: chunk compose (lean LDS, bf16 B)
__global__ __launch_bounds__(256) void k4a_scanA(
    const float* __restrict__ dltf, const float* __restrict__ dltr,
    const float* __restrict__ dtwf, const float* __restrict__ dtbf,
    const float* __restrict__ dtwr, const float* __restrict__ dtbr,
    const float* __restrict__ uf,  const float* __restrict__ ur,
    const unsigned short* __restrict__ Bf, const unsigned short* __restrict__ Br,
    const float* __restrict__ Alf, const float* __restrict__ Alr,
    float* __restrict__ P, float* __restrict__ S)
{
  __shared__ float sU[64*64];
  __shared__ unsigned short sB[64*16];
  __shared__ float4 sDlt[64];
  int tid = threadIdx.x;
  int bx = blockIdx.x;
  int c = bx & (NCH-1), dir = (bx >> 8) & 1, b = bx >> 9;
  const float* dlt = dir ? dltr : dltf;
  const float* u   = dir ? ur  : uf;
  const unsigned short* Bm = dir ? Br : Bf;
  const float* Al  = dir ? Alr : Alf;
  const float* dtw = dir ? dtwr : dtwf;
  const float* dtb = dir ? dtbr : dtbf;
  size_t t0 = (size_t)b*SEQL + (dir ? (SEQL - (size_t)(c+1)*CHL) : (size_t)c*CHL);
  {
    const float4* gu = (const float4*)(u + t0*64);
    #pragma unroll
    for (int i = 0; i < 4; ++i)
      ((float4*)sU)[tid + i*256] = gu[tid + i*256];
    ((uint2*)sB)[tid] = ((const uint2*)(Bm + t0*16))[tid];
    if (tid < 64) sDlt[tid] = ((const float4*)(dlt + t0*4))[tid];
  }
  __syncthreads();
  int lane = tid & 63, wv = tid >> 6;
  int nq = lane >> 4;
  int d = wv*16 + (lane & 15);
  float4 wd = ((const float4*)dtw)[d];
  float bd = dtb[d];
  float A2[4], Pp[4] = {1.f,1.f,1.f,1.f}, Ss[4] = {0.f,0.f,0.f,0.f};
  #pragma unroll
  for (int j = 0; j < 4; ++j)
    A2[j] = -__expf(Al[d*16 + nq*4 + j]) * 1.44269504f;
  #pragma unroll 4
  for (int i = 0; i < CHL; ++i){
    int li = dir ? (CHL-1-i) : i;
    float4 dl = sDlt[li];
    float dtv = softplus_fast(fmaf(wd.x,dl.x, fmaf(wd.y,dl.y,
                              fmaf(wd.z,dl.z, fmaf(wd.w,dl.w, bd)))));
    float uv  = sU[li*64 + d];
    float du  = dtv * uv;
    float bb[4];
    b4f(*(const uint2*)&sB[li*16 + nq*4], bb);
    #pragma unroll
    for (int j = 0; j < 4; ++j){
      float a = exp2f(dtv*A2[j]);
      Pp[j] *= a;
      Ss[j] = fmaf(a, Ss[j], du*bb[j]);
    }
  }
  size_t pidx = (((size_t)(b*2+dir)*NCH + c)*64 + d)*16 + nq*4;
  *(float4*)(P + pidx) = make_float4(Pp[0],Pp[1],Pp[2],Pp[3]);
  *(float4*)(S + pidx) = make_float4(Ss[0],Ss[1],Ss[2],Ss[3]);
}

// ================================================================ K4b: Kogge-Stone carry scan
__global__ __launch_bounds__(256) void k4b_ks(float* __restrict__ P,
                                              const float* __restrict__ S)
{
  __shared__ float Pl[256*18], Sl[256*18];
  int c = threadIdx.x;
  int d = blockIdx.x & 63, bd = blockIdx.x >> 6;
  size_t idx = (((size_t)bd*NCH + c)*64 + d)*16;
  float p[16], s[16];
  #pragma unroll
  for (int k = 0; k < 4; k++){
    float4 pv = ((const float4*)(P + idx))[k];
    float4 sv = ((const float4*)(S + idx))[k];
    p[4*k]=pv.x; p[4*k+1]=pv.y; p[4*k+2]=pv.z; p[4*k+3]=pv.w;
    s[4*k]=sv.x; s[4*k+1]=sv.y; s[4*k+2]=sv.z; s[4*k+3]=sv.w;
  }
  #pragma unroll
  for (int j = 0; j < 8; j++){
    *(float2*)&Pl[c*18 + 2*j] = make_float2(p[2*j], p[2*j+1]);
    *(float2*)&Sl[c*18 + 2*j] = make_float2(s[2*j], s[2*j+1]);
  }
  for (int step = 1; step < NCH; step <<= 1){
    __syncthreads();
    float pp[16], ss[16];
    bool act = (c >= step);
    if (act){
      #pragma unroll
      for (int j = 0; j < 8; j++){
        float2 tp = *(const float2*)&Pl[(c-step)*18 + 2*j];
        float2 ts = *(const float2*)&Sl[(c-step)*18 + 2*j];
        pp[2*j]=tp.x; pp[2*j+1]=tp.y; ss[2*j]=ts.x; ss[2*j+1]=ts.y;
      }
    }
    __syncthreads();
    if (act){
      #pragma unroll
      for (int n = 0; n < 16; n++){
        s[n] = fmaf(p[n], ss[n], s[n]);
        p[n] *= pp[n];
      }
      #pragma unroll
      for (int j = 0; j < 8; j++){
        *(float2*)&Pl[c*18 + 2*j] = make_float2(p[2*j], p[2*j+1]);
        *(float2*)&Sl[c*18 + 2*j] = make_float2(s[2*j], s[2*j+1]);
      }
    }
  }
  __syncthreads();
  float ho[16];
  if (c == 0){
    #pragma unroll
    for (int n = 0; n < 16; n++) ho[n] = 0.f;
  } else {
    #pragma unroll
    for (int j = 0; j < 8; j++){
      float2 ts = *(const float2*)&Sl[(c-1)*18 + 2*j];
      ho[2*j]=ts.x; ho[2*j+1]=ts.y;
    }
  }
  #pragma unroll
  for (int k = 0; k < 4; k++)
    ((float4*)(P + idx))[k] = make_float4(ho[4*k], ho[4*k+1], ho[4*k+2], ho[4*k+3]);
}

// ================================================================ K5: fused scanB(both dirs) + epilogue
// block = (b, 64-token window w): fwd chunk w + rev chunk NCH-1-w cover the
// same tokens. Scan both dirs from LDS (2 independent chains), yf/yr -> bf16
// LDS, then: silu-merge (z from global), RMS, out_proj MFMA, post-LN, gate, skip.
__device__ __forceinline__ float scan_step(
    int li, const float4* __restrict__ sDl, const float* __restrict__ sU,
    const unsigned short* __restrict__ sB, const unsigned short* __restrict__ sC,
    float4 wd, float bd, float Dd, const float (&A2)[4], float (&h)[4],
    int d, int nq)
{
  float4 dl = sDl[li];
  float dtv = softplus_fast(fmaf(wd.x,dl.x, fmaf(wd.y,dl.y,
                            fmaf(wd.z,dl.z, fmaf(wd.w,dl.w, bd)))));
  float uv = sU[li*64 + d];
  float du = dtv * uv;
  float bb[4], cc[4];
  b4f(*(const uint2*)&sB[li*16 + nq*4], bb);
  b4f(*(const uint2*)&sC[li*16 + nq*4], cc);
  float yv = nq ? 0.f : uv*Dd;
  #pragma unroll
  for (int j = 0; j < 4; ++j){
    float a = exp2f(dtv*A2[j]);
    h[j] = fmaf(a, h[j], du*bb[j]);
    yv = fmaf(h[j], cc[j], yv);
  }
  return yv;
}

__global__ __launch_bounds__(256) void k5_fused(
    const float* __restrict__ dltf, const float* __restrict__ dltr,
    const float* __restrict__ dtwf, const float* __restrict__ dtbf,
    const float* __restrict__ dtwr, const float* __restrict__ dtbr,
    const float* __restrict__ uf,  const float* __restrict__ ur,
    const unsigned short* __restrict__ Bfg, const unsigned short* __restrict__ Cfg,
    const unsigned short* __restrict__ Brg, const unsigned short* __restrict__ Crg,
    const float* __restrict__ Alf, const float* __restrict__ Alr,
    const float* __restrict__ Dvf, const float* __restrict__ Dvr,
    const float* __restrict__ Hpre,
    const unsigned short* __restrict__ zb, const unsigned short* __restrict__ zeb,
    const float* __restrict__ wg, const float* __restrict__ x0n,
    const float* __restrict__ in0,
    const float* __restrict__ mnw, const float* __restrict__ opw,
    const float* __restrict__ pnw, const float* __restrict__ pnb,
    float* __restrict__ out)
{
  __shared__ __align__(16) char smem[59392];
  float* sUf = (float*)(smem);                             // 16384
  float* sUr = (float*)(smem + 16384);                     // 16384
  unsigned short* sBf = (unsigned short*)(smem + 32768);   // 2048 each
  unsigned short* sCf = (unsigned short*)(smem + 34816);
  unsigned short* sBr = (unsigned short*)(smem + 36864);
  unsigned short* sCr = (unsigned short*)(smem + 38912);
  float4* sDlf = (float4*)(smem + 40960);                  // 1024 each
  float4* sDlr = (float4*)(smem + 41984);
  unsigned short* sYf = (unsigned short*)(smem + 43008);   // 8192 each
  unsigned short* sYr = (unsigned short*)(smem + 51200);
  // phase-2 aliases (scan-phase regions dead by then)
  short* Wl = (short*)(smem);                              // 9216
  short* Al = (short*)(smem + 16384);                      // 9216 (ends 25600)
  float* Dbuf = (float*)(smem + 25600);                    // 16896 (ends 42496 < 43008)

  int tid = threadIdx.x;
  int bx = blockIdx.x;
  int w = bx & 255, b = bx >> 8;
  size_t t0 = (size_t)b*SEQL + (size_t)w*64;
  int cf = w, cr = NCH-1-w;
  // ---- stage
  {
    const float4* gu = (const float4*)(uf + t0*64);
    const float4* gr = (const float4*)(ur + t0*64);
    #pragma unroll
    for (int i = 0; i < 4; ++i){
      ((float4*)sUf)[tid + i*256] = gu[tid + i*256];
      ((float4*)sUr)[tid + i*256] = gr[tid + i*256];
    }
    ((uint2*)sBf)[tid] = ((const uint2*)(Bfg + t0*16))[tid];
    ((uint2*)sCf)[tid] = ((const uint2*)(Cfg + t0*16))[tid];
    ((uint2*)sBr)[tid] = ((const uint2*)(Brg + t0*16))[tid];
    ((uint2*)sCr)[tid] = ((const uint2*)(Crg + t0*16))[tid];
    if (tid < 64) sDlf[tid] = ((const float4*)(dltf + t0*4))[tid];
    else if (tid < 128) sDlr[tid-64] = ((const float4*)(dltr + t0*4))[tid-64];
  }
  __syncthreads();
  // ---- dual-direction scan
  int lane = tid & 63, wv = tid >> 6;
  int nq = lane >> 4;
  int d = wv*16 + (lane & 15);
  float4 wdf = ((const float4*)dtwf)[d];
  float4 wdr = ((const float4*)dtwr)[d];
  float bdf = dtbf[d], bdr = dtbr[d];
  float Ddf = Dvf[d], Ddr = Dvr[d];
  float A2f[4], A2r[4], hf[4], hr[4];
  #pragma unroll
  for (int j = 0; j < 4; ++j){
    A2f[j] = -__expf(Alf[d*16 + nq*4 + j]) * 1.44269504f;
    A2r[j] = -__expf(Alr[d*16 + nq*4 + j]) * 1.44269504f;
  }
  {
    size_t pif = (((size_t)(b*2+0)*NCH + cf)*64 + d)*16 + nq*4;
    size_t pir = (((size_t)(b*2+1)*NCH + cr)*64 + d)*16 + nq*4;
    float4 h4f = *(const float4*)(Hpre + pif);
    float4 h4r = *(const float4*)(Hpre + pir);
    hf[0]=h4f.x; hf[1]=h4f.y; hf[2]=h4f.z; hf[3]=h4f.w;
    hr[0]=h4r.x; hr[1]=h4r.y; hr[2]=h4r.z; hr[3]=h4r.w;
  }
  for (int i = 0; i < CHL; i += 2){
    float y0 = scan_step(i,    sDlf, sUf, sBf, sCf, wdf, bdf, Ddf, A2f, hf, d, nq);
    float y1 = scan_step(i+1,  sDlf, sUf, sBf, sCf, wdf, bdf, Ddf, A2f, hf, d, nq);
    float y2 = scan_step(63-i,   sDlr, sUr, sBr, sCr, wdr, bdr, Ddr, A2r, hr, d, nq);
    float y3 = scan_step(63-i-1, sDlr, sUr, sBr, sCr, wdr, bdr, Ddr, A2r, hr, d, nq);
    y0 += __shfl_xor(y0, 16, 64);
    y1 += __shfl_xor(y1, 16, 64);
    y2 += __shfl_xor(y2, 16, 64);
    y3 += __shfl_xor(y3, 16, 64);
    y0 += __shfl_xor(y0, 32, 64);
    y1 += __shfl_xor(y1, 32, 64);
    y2 += __shfl_xor(y2, 32, 64);
    y3 += __shfl_xor(y3, 32, 64);
    if (nq == 0){
      sYf[ i      *64 + d] = f2b(y0);
      sYf[(i+1)   *64 + d] = f2b(y1);
      sYr[(63-i)  *64 + d] = f2b(y2);
      sYr[(63-i-1)*64 + d] = f2b(y3);
    }
  }
  __syncthreads();
  // ---- phase 2: Wl stage + silu-merge + RMS -> Al (bf16)
  for (int sseg = tid; sseg < 64*8; sseg += 256){
    int row = sseg >> 3, sg = sseg & 7;
    const float* src = opw + (size_t)row*64 + sg*8;
    float4 f0 = ((const float4*)src)[0];
    float4 f1 = ((const float4*)src)[1];
    short8 v;
    v[0]=(short)f2b(f0.x); v[1]=(short)f2b(f0.y); v[2]=(short)f2b(f0.z); v[3]=(short)f2b(f0.w);
    v[4]=(short)f2b(f1.x); v[5]=(short)f2b(f1.y); v[6]=(short)f2b(f1.z); v[7]=(short)f2b(f1.w);
    *(short8*)&Wl[row*72 + sg*8] = v;
  }
  {
    int tl = tid >> 2, p = tid & 3;
    size_t g = (t0 + tl)*64 + p*16;
    short8 yf8a = *(const short8*)&sYf[tl*64 + p*16];
    short8 yf8b = *(const short8*)&sYf[tl*64 + p*16 + 8];
    short8 yr8a = *(const short8*)&sYr[tl*64 + p*16];
    short8 yr8b = *(const short8*)&sYr[tl*64 + p*16 + 8];
    short8 z8a  = *(const short8*)(zb + g);
    short8 z8b  = *(const short8*)(zb + g + 8);
    short8 ze8a = *(const short8*)(zeb + g);
    short8 ze8b = *(const short8*)(zeb + g + 8);
    float vy[16]; float ss = 0.f;
    #pragma unroll
    for (int i = 0; i < 16; i++){
      float yfv = b2f((unsigned short)(i < 8 ? yf8a[i] : yf8b[i-8]));
      float yrv = b2f((unsigned short)(i < 8 ? yr8a[i] : yr8b[i-8]));
      float zv  = b2f((unsigned short)(i < 8 ? z8a[i]  : z8b[i-8]));
      float zev = b2f((unsigned short)(i < 8 ? ze8a[i] : ze8b[i-8]));
      float v = 0.5f*(yfv*siluf(zv) + yrv*siluf(zev));
      vy[i] = v; ss += v*v;
    }
    ss += __shfl_xor(ss, 1, 64);
    ss += __shfl_xor(ss, 2, 64);
    float rms = rsqrtf(ss*(1.f/64.f) + 1e-5f);
    #pragma unroll
    for (int i = 0; i < 16; i++){
      float wmn = mnw[p*16 + i];
      Al[tl*72 + p*16 + i] = (short)f2b(vy[i]*rms*wmn);
    }
  }
  __syncthreads();
  // ---- phase 3: out_proj MFMA
  int n = lane & 15, q = lane >> 4;
  {
    short8 a0 = *(const short8*)&Al[(wv*16 + n)*72 + q*8];
    short8 a1 = *(const short8*)&Al[(wv*16 + n)*72 + 32 + q*8];
    #pragma unroll
    for (int o = 0; o < 4; ++o){
      short8 b0 = *(const short8*)&Wl[(o*16 + n)*72 + q*8];
      short8 b1 = *(const short8*)&Wl[(o*16 + n)*72 + 32 + q*8];
      f32x4 c = {0.f, 0.f, 0.f, 0.f};
      c = __builtin_amdgcn_mfma_f32_16x16x32_bf16(a0, b0, c, 0, 0, 0);
      c = __builtin_amdgcn_mfma_f32_16x16x32_bf16(a1, b1, c, 0, 0, 0);
      #pragma unroll
      for (int r = 0; r < 4; ++r)
        Dbuf[(wv*16 + q*4 + r)*66 + o*16 + n] = c[r];
    }
  }
  __syncthreads();
  // ---- phase 4: post-LN + gate + skip
  float gpw = pnw[lane], gpb = pnb[lane];
  float s1, s2;
  for (int i = 0; i < 16; ++i){
    int tl = wv*16 + i;
    size_t off = (t0 + tl)*64 + lane;
    float v = Dbuf[tl*66 + lane];
    s1 = v; s2 = v*v;
    #pragma unroll
    for (int o2 = 32; o2 > 0; o2 >>= 1){ s1 += __shfl_xor(s1,o2,64); s2 += __shfl_xor(s2,o2,64); }
    float m = s1*(1.f/64.f);
    float qv = s2*(1.f/64.f) - m*m;
    float o = (v-m)*rsqrtf(qv+1e-5f)*gpw + gpb;
    o = nan2num(o, 0.f, 1.f, -1.f);
    float wgt = wg[off];
    float skip = nan2num(in0[off], 0.f, 1.f, -1.f);
    out[off] = fmaf(o, wgt, fmaf(x0n[off], 1.f - wgt, skip));
  }
}

// ================================================================ launcher
extern "C" void kernel_launch(void* const* d_in, const int* in_sizes, int n_in,
                              void* d_out, int out_size, void* d_ws, size_t ws_size,
                              hipStream_t stream)
{
  (void)in_sizes; (void)n_in; (void)out_size; (void)ws_size;
  const float* in0  = (const float*)d_in[0];
  const float* in1  = (const float*)d_in[1];
  const float* n0w  = (const float*)d_in[2];
  const float* n0b  = (const float*)d_in[3];
  const float* n1w  = (const float*)d_in[4];
  const float* n1b  = (const float*)d_in[5];
  const float* cww  = (const float*)d_in[6];
  const float* cwb  = (const float*)d_in[7];
  const float* cwnw = (const float*)d_in[8];
  const float* cwnb = (const float*)d_in[9];
  const float* ipw  = (const float*)d_in[10];
  const float* ipew = (const float*)d_in[11];
  const float* cwf  = (const float*)d_in[12];
  const float* cbf  = (const float*)d_in[13];
  const float* xpwf = (const float*)d_in[14];
  const float* dtwf = (const float*)d_in[15];
  const float* dtbf = (const float*)d_in[16];
  const float* Alf  = (const float*)d_in[17];
  const float* Dvf  = (const float*)d_in[18];
  const float* cwr  = (const float*)d_in[19];
  const float* cbr  = (const float*)d_in[20];
  const float* xpwr = (const float*)d_in[21];
  const float* dtwr = (const float*)d_in[22];
  const float* dtbr = (const float*)d_in[23];
  const float* Alr  = (const float*)d_in[24];
  const float* Dvr  = (const float*)d_in[25];
  const float* mnw  = (const float*)d_in[26];
  const float* opw  = (const float*)d_in[27];
  const float* pnw  = (const float*)d_in[28];
  const float* pnb  = (const float*)d_in[29];

  float* ws  = (float*)d_ws;
  float* x0n = ws + 0*EL;
  float* xa  = ws + 1*EL;
  float* xe  = ws + 2*EL;
  float* uf  = ws + 3*EL;
  float* ur  = ws + 4*EL;
  float* wg  = ws + 5*EL;
  unsigned short* Bf = (unsigned short*)(ws + 6*EL);   // TOK*16 ushorts each
  unsigned short* Cf = Bf + (size_t)TOK*16;
  unsigned short* Br = Cf + (size_t)TOK*16;
  unsigned short* Cr = Br + (size_t)TOK*16;
  float* P   = ws + 7*EL;              // 2*TOK*16 floats = 8 MB
  float* S   = P + 2*(size_t)TOK*16;   // 8 MB
  unsigned short* zb  = (unsigned short*)(ws + 8*EL);
  unsigned short* zeb = zb + EL;
  float* dltf = ws + 9*EL;             // TOK*4 each
  float* dltr = dltf + (size_t)TOK*4;

  mega1<<<512, 256, 0, stream>>>(in0, in1, n0w, n0b, n1w, n1b, cww, cwb,
                                 cwnw, cwnb, ipw, ipew,
                                 x0n, wg, xa, xe, zb, zeb);
  g2_convproj<<<512, 256, 0, stream>>>(xa, xe, cwf, cbf, cwr, cbr,
                                       xpwf, xpwr,
                                       uf, ur, dltf, dltr, Bf, Cf, Br, Cr);
  k4a_scanA<<<2048, 256, 0, stream>>>(dltf, dltr, dtwf, dtbf, dtwr, dtbr,
                                      uf, ur, Bf, Br, Alf, Alr, P, S);
  k4b_ks<<<512, 256, 0, stream>>>(P, S);
  k5_fused<<<1024, 256, 0, stream>>>(dltf, dltr, dtwf, dtbf, dtwr, dtbr,
                                     uf, ur, Bf, Cf, Br, Cr,
                                     Alf, Alr, Dvf, Dvr, P,
                                     zb, zeb, wg, x0n, in0,
                                     mnw, opw, pnw, pnb, (float*)d_out);
}

// Round 10
// 327.400 us; speedup vs baseline: 1.0852x; 1.0852x over previous
//
#include <hip/hip_runtime.h>
#include <stdint.h>

#define BATCH 4
#define SEQL  16384
#define DIM   64
#define NST   16
#define TOK   (BATCH*SEQL)        /* 65536 tokens */
#define EL    ((size_t)TOK*DIM)   /* 4194304 elems per [B,L,D] array */
#define NCH   256                 /* chunks per (b,dir) */
#define CHL   64                  /* chunk length; NCH*CHL == SEQL */

typedef __attribute__((ext_vector_type(8))) short short8;
typedef __attribute__((ext_vector_type(4))) float f32x4;

__device__ __forceinline__ float nan2num(float x, float nv, float pv, float mv){
  if (__builtin_isnan(x)) return nv;
  if (__builtin_isinf(x)) return x > 0.f ? pv : mv;
  return x;
}
__device__ __forceinline__ float siluf(float x){ return x / (1.f + __expf(-x)); }
__device__ __forceinline__ float b2f(unsigned short s){
  union { unsigned u; float f; } v; v.u = ((unsigned)s) << 16; return v.f;
}
__device__ __forceinline__ unsigned short f2b(float f){
  union { float f; unsigned u; } v; v.f = f;
  unsigned r = v.u + 0x7fffu + ((v.u >> 16) & 1u);   // RNE
  return (unsigned short)(r >> 16);
}
__device__ __forceinline__ void b4fu(uint2 v, float* o){
  o[0] = b2f((unsigned short)(v.x & 0xffff));
  o[1] = b2f((unsigned short)(v.x >> 16));
  o[2] = b2f((unsigned short)(v.y & 0xffff));
  o[3] = b2f((unsigned short)(v.y >> 16));
}
// fast softplus: ln(1+e^x) = log2(1+2^(x*log2e))*ln2  (HW v_exp/v_log, no libm)
__device__ __forceinline__ float softplus_fast(float x){
  if (x > 20.f) return x;
  float t = exp2f(x * 1.44269504f);
  return __log2f(1.f + t) * 0.69314718f;
}

// ================================================================ MEGA1
__global__ __launch_bounds__(256) void mega1(
    const float* __restrict__ in0, const float* __restrict__ in1,
    const float* __restrict__ n0w, const float* __restrict__ n0b,
    const float* __restrict__ n1w, const float* __restrict__ n1b,
    const float* __restrict__ cww, const float* __restrict__ cwb,
    const float* __restrict__ cwnw, const float* __restrict__ cwnb,
    const float* __restrict__ ipw, const float* __restrict__ ipew,
    float* __restrict__ x0n, float* __restrict__ wg,
    float* __restrict__ xa,  float* __restrict__ xe,
    unsigned short* __restrict__ zb, unsigned short* __restrict__ zeb)
{
  __shared__ __align__(16) short Wl[192*72];
  __shared__ __align__(16) short Al[128*72];
  int tid = threadIdx.x;
  int t0 = blockIdx.x * 128;
  int lane = tid & 63, wv = tid >> 6;
  int n = lane & 15, q = lane >> 4;
  f32x4 wacc[2][4];

  #pragma unroll
  for (int s = 0; s < 2; ++s){
    const float* ips = s ? ipew : ipw;
    for (int sseg = tid; sseg < 192*8; sseg += 256){
      int row = sseg >> 3, sg = sseg & 7;
      const float* src = (row < 64) ? (cww + (size_t)row*128 + s*64 + sg*8)
                                    : (ips + (size_t)(row-64)*64 + sg*8);
      float4 f0 = ((const float4*)src)[0];
      float4 f1 = ((const float4*)src)[1];
      short8 v;
      v[0]=(short)f2b(f0.x); v[1]=(short)f2b(f0.y); v[2]=(short)f2b(f0.z); v[3]=(short)f2b(f0.w);
      v[4]=(short)f2b(f1.x); v[5]=(short)f2b(f1.y); v[6]=(short)f2b(f1.z); v[7]=(short)f2b(f1.w);
      *(short8*)&Wl[row*72 + sg*8] = v;
    }
    {
      const float* inp = s ? in1 : in0;
      const float* nw  = s ? n1w : n0w;
      const float* nb  = s ? n1b : n0b;
      int tl = tid >> 2, p = tid & 3;
      float gw[16], gb[16];
      #pragma unroll
      for (int i = 0; i < 4; ++i){
        float4 w4 = ((const float4*)(nw + p*16))[i];
        float4 b4 = ((const float4*)(nb + p*16))[i];
        gw[4*i]=w4.x; gw[4*i+1]=w4.y; gw[4*i+2]=w4.z; gw[4*i+3]=w4.w;
        gb[4*i]=b4.x; gb[4*i+1]=b4.y; gb[4*i+2]=b4.z; gb[4*i+3]=b4.w;
      }
      #pragma unroll
      for (int sp = 0; sp < 2; ++sp){
        int tok_l = sp*64 + tl;
        size_t ga = ((size_t)(t0 + tok_l))*64 + p*16;
        float v[16]; float s1 = 0.f, s2 = 0.f;
        #pragma unroll
        for (int i = 0; i < 4; ++i){
          float4 f = ((const float4*)(inp + ga))[i];
          float a0 = nan2num(f.x,0.f,1.f,-1.f), a1 = nan2num(f.y,0.f,1.f,-1.f);
          float a2 = nan2num(f.z,0.f,1.f,-1.f), a3 = nan2num(f.w,0.f,1.f,-1.f);
          v[4*i]=a0; v[4*i+1]=a1; v[4*i+2]=a2; v[4*i+3]=a3;
          s1 += a0+a1+a2+a3; s2 += a0*a0+a1*a1+a2*a2+a3*a3;
        }
        s1 += __shfl_xor(s1,1,64); s1 += __shfl_xor(s1,2,64);
        s2 += __shfl_xor(s2,1,64); s2 += __shfl_xor(s2,2,64);
        float m = s1*(1.f/64.f);
        float var = s2*(1.f/64.f) - m*m;
        float rs = rsqrtf(var + 1e-5f);
        float xr[16];
        #pragma unroll
        for (int i = 0; i < 16; ++i){
          float x = nan2num((v[i]-m)*rs*gw[i] + gb[i], 0.f, 1.f, -1.f);
          xr[i] = x;
          Al[tok_l*72 + p*16 + i] = (short)f2b(x);
        }
        if (s == 0){
          #pragma unroll
          for (int i = 0; i < 4; ++i)
            ((float4*)(x0n + ga))[i] = make_float4(xr[4*i],xr[4*i+1],xr[4*i+2],xr[4*i+3]);
        }
      }
    }
    __syncthreads();
    float* outx = s ? xe : xa;
    unsigned short* outz = s ? zeb : zb;
    #pragma unroll
    for (int mi = 0; mi < 2; ++mi){
      int mt = wv*2 + mi;
      short8 a0 = *(const short8*)&Al[(mt*16 + n)*72 + q*8];
      short8 a1 = *(const short8*)&Al[(mt*16 + n)*72 + 32 + q*8];
      #pragma unroll
      for (int o = 0; o < 12; ++o){
        short8 b0 = *(const short8*)&Wl[(o*16 + n)*72 + q*8];
        short8 b1 = *(const short8*)&Wl[(o*16 + n)*72 + 32 + q*8];
        f32x4 c = {0.f, 0.f, 0.f, 0.f};
        c = __builtin_amdgcn_mfma_f32_16x16x32_bf16(a0, b0, c, 0, 0, 0);
        c = __builtin_amdgcn_mfma_f32_16x16x32_bf16(a1, b1, c, 0, 0, 0);
        if (o < 4){
          if (s == 0) wacc[mi][o] = c; else wacc[mi][o] += c;
        } else if (o < 8){
          #pragma unroll
          for (int r = 0; r < 4; ++r)
            outx[((size_t)(t0 + mt*16 + q*4 + r))*64 + (o-4)*16 + n] = c[r];
        } else {
          #pragma unroll
          for (int r = 0; r < 4; ++r)
            outz[((size_t)(t0 + mt*16 + q*4 + r))*64 + (o-8)*16 + n] = f2b(c[r]);
        }
      }
    }
    if (s == 0) __syncthreads();
  }
  float cb_l[4], gnw[4], gnb[4];
  #pragma unroll
  for (int o = 0; o < 4; ++o){
    cb_l[o] = cwb[o*16+n]; gnw[o] = cwnw[o*16+n]; gnb[o] = cwnb[o*16+n];
  }
  #pragma unroll
  for (int mi = 0; mi < 2; ++mi){
    #pragma unroll
    for (int r = 0; r < 4; ++r){
      float v[4]; float sv = 0.f, sq = 0.f;
      #pragma unroll
      for (int o = 0; o < 4; ++o){
        v[o] = wacc[mi][o][r] + cb_l[o];
        sv += v[o]; sq += v[o]*v[o];
      }
      sv += __shfl_xor(sv,1,64); sv += __shfl_xor(sv,2,64);
      sv += __shfl_xor(sv,4,64); sv += __shfl_xor(sv,8,64);
      sq += __shfl_xor(sq,1,64); sq += __shfl_xor(sq,2,64);
      sq += __shfl_xor(sq,4,64); sq += __shfl_xor(sq,8,64);
      float m = sv*(1.f/64.f);
      float var = sq*(1.f/64.f) - m*m;
      float rs = rsqrtf(var + 1e-5f);
      size_t tok = (size_t)t0 + (wv*2+mi)*16 + q*4 + r;
      #pragma unroll
      for (int o = 0; o < 4; ++o){
        float wn = (v[o]-m)*rs*gnw[o] + gnb[o];
        wn = nan2num(wn, 0.5f, 1.f, 0.f);
        wn = 1.f/(1.f + __expf(-wn));
        wn = fminf(fmaxf(wn, 0.01f), 0.99f);
        wg[tok*64 + o*16 + n] = wn;
      }
    }
  }
}

// ================================================================ G2: conv + xproj
__global__ __launch_bounds__(256) void g2_convproj(
    const float* __restrict__ xa, const float* __restrict__ xe,
    const float* __restrict__ cwf, const float* __restrict__ cbf,
    const float* __restrict__ cwr, const float* __restrict__ cbr,
    const float* __restrict__ xpwf, const float* __restrict__ xpwr,
    float* __restrict__ uf, float* __restrict__ ur,
    float* __restrict__ dltf, float* __restrict__ dltr,
    unsigned short* __restrict__ Bf, unsigned short* __restrict__ Cf,
    unsigned short* __restrict__ Br, unsigned short* __restrict__ Cr)
{
  __shared__ __align__(16) short Wl[2*48*72];
  __shared__ __align__(16) short Al[2*128*72];
  int tid = threadIdx.x;
  int b = blockIdx.x >> 7, l0 = (blockIdx.x & 127) * 128;
  size_t base = (size_t)b * SEQL;
  for (int sseg = tid; sseg < 2*48*8; sseg += 256){
    int s = sseg >= 48*8;
    int rs = sseg - s*48*8;
    int row = rs >> 3, sg = rs & 7;
    const float* xp = s ? xpwr : xpwf;
    short8 v = {0,0,0,0,0,0,0,0};
    int srcrow = (row < 32) ? (4+row) : (row < 36) ? (row-32) : -1;
    if (srcrow >= 0){
      const float* src = xp + (size_t)srcrow*64 + sg*8;
      float4 f0 = ((const float4*)src)[0];
      float4 f1 = ((const float4*)src)[1];
      v[0]=(short)f2b(f0.x); v[1]=(short)f2b(f0.y); v[2]=(short)f2b(f0.z); v[3]=(short)f2b(f0.w);
      v[4]=(short)f2b(f1.x); v[5]=(short)f2b(f1.y); v[6]=(short)f2b(f1.z); v[7]=(short)f2b(f1.w);
    }
    *(short8*)&Wl[(s*48+row)*72 + sg*8] = v;
  }
  {
    int d = tid & 63, lq = tid >> 6;
    float4 wf4 = ((const float4*)cwf)[d];
    float4 wr4 = ((const float4*)cwr)[d];
    float bf = cbf[d], brr = cbr[d];
    for (int i = 0; i < 8; ++i){
      int ll = i*16 + lq*4;
      int gl = l0 + ll;
      float rv[7], sv[7];
      #pragma unroll
      for (int j = 0; j < 7; ++j){
        int li = gl - 3 + j;
        rv[j] = (li >= 0) ? xa[(base + li)*64 + d] : 0.f;
        int lj = gl + j;
        sv[j] = (lj < SEQL) ? xe[(base + lj)*64 + d] : 0.f;
      }
      #pragma unroll
      for (int k = 0; k < 4; ++k){
        float a = bf + wf4.x*rv[k] + wf4.y*rv[k+1] + wf4.z*rv[k+2] + wf4.w*rv[k+3];
        a = siluf(a);
        uf[(base + gl + k)*64 + d] = a;
        Al[(ll+k)*72 + d] = (short)f2b(a);
        float r = brr + wr4.w*sv[k] + wr4.z*sv[k+1] + wr4.y*sv[k+2] + wr4.x*sv[k+3];
        r = siluf(r);
        ur[(base + gl + k)*64 + d] = r;
        Al[(128 + ll + k)*72 + d] = (short)f2b(r);
      }
    }
  }
  __syncthreads();
  int lane = tid & 63, wv = tid >> 6;
  int n = lane & 15, q = lane >> 4;
  #pragma unroll
  for (int s = 0; s < 2; ++s){
    const short* As = &Al[s*128*72];
    const short* Ws = &Wl[s*48*72];
    unsigned short* Bo = s ? Br : Bf;
    unsigned short* Co = s ? Cr : Cf;
    float* Do = s ? dltr : dltf;
    #pragma unroll
    for (int mi = 0; mi < 2; ++mi){
      int mt = wv*2 + mi;
      short8 a0 = *(const short8*)&As[(mt*16 + n)*72 + q*8];
      short8 a1 = *(const short8*)&As[(mt*16 + n)*72 + 32 + q*8];
      f32x4 acc[3];
      #pragma unroll
      for (int o = 0; o < 3; ++o){
        short8 b0 = *(const short8*)&Ws[(o*16 + n)*72 + q*8];
        short8 b1 = *(const short8*)&Ws[(o*16 + n)*72 + 32 + q*8];
        f32x4 c = {0.f, 0.f, 0.f, 0.f};
        c = __builtin_amdgcn_mfma_f32_16x16x32_bf16(a0, b0, c, 0, 0, 0);
        c = __builtin_amdgcn_mfma_f32_16x16x32_bf16(a1, b1, c, 0, 0, 0);
        acc[o] = c;
      }
      #pragma unroll
      for (int r = 0; r < 4; ++r){
        size_t tok = base + l0 + mt*16 + q*4 + r;
        Bo[tok*16 + n] = f2b(acc[0][r]);
        Co[tok*16 + n] = f2b(acc[1][r]);
        if (n < 4) Do[tok*4 + n] = acc[2][r];
      }
    }
  }
}

// ================================================================ K4a: chunk compose
// block = 4 chunks of one (b,dir), wave per chunk, lane = d, 16 states/thread.
// No cross-lane ops in scan loop; LDS reads broadcast or 2-way (free).
__global__ __launch_bounds__(256) void k4a_scanA(
    const float* __restrict__ dltf, const float* __restrict__ dltr,
    const float* __restrict__ dtwf, const float* __restrict__ dtbf,
    const float* __restrict__ dtwr, const float* __restrict__ dtbr,
    const float* __restrict__ uf,  const float* __restrict__ ur,
    const unsigned short* __restrict__ Bf, const unsigned short* __restrict__ Br,
    const float* __restrict__ Alf, const float* __restrict__ Alr,
    float* __restrict__ P, float* __restrict__ S)
{
  __shared__ unsigned short sU[256*64];   // 32 KB bf16
  __shared__ unsigned short sB[256*16];   // 8 KB bf16
  __shared__ float4 sDlt[256];            // 4 KB
  int tid = threadIdx.x;
  int bx = blockIdx.x;                    // 512 = b(4) x dir(2) x w(64)
  int w = bx & 63, dir = (bx >> 6) & 1, b = bx >> 7;
  const float* dlt = dir ? dltr : dltf;
  const float* u   = dir ? ur  : uf;
  const unsigned short* Bm = dir ? Br : Bf;
  const float* Al  = dir ? Alr : Alf;
  const float* dtw = dir ? dtwr : dtwf;
  const float* dtb = dir ? dtbr : dtbf;
  size_t t0 = (size_t)b*SEQL + (dir ? (SEQL - (size_t)(w+1)*256) : (size_t)w*256);
  // ---- stage 256-token window
  {
    const float4* gu = (const float4*)(u + t0*64);
    #pragma unroll
    for (int i = 0; i < 16; ++i){
      float4 v = gu[tid + i*256];
      uint2 pk;
      pk.x = (unsigned)f2b(v.x) | ((unsigned)f2b(v.y) << 16);
      pk.y = (unsigned)f2b(v.z) | ((unsigned)f2b(v.w) << 16);
      ((uint2*)sU)[tid + i*256] = pk;
    }
    #pragma unroll
    for (int i = 0; i < 4; ++i)
      ((uint2*)sB)[tid + i*256] = ((const uint2*)(Bm + t0*16))[tid + i*256];
    sDlt[tid] = ((const float4*)(dlt + t0*4))[tid];
  }
  __syncthreads();
  int lane = tid & 63, wv = tid >> 6;
  int d = lane;
  int c = w*4 + wv;
  float4 wd = ((const float4*)dtw)[d];
  float bd = dtb[d];
  float A2[16], Pp[16], Ss[16];
  #pragma unroll
  for (int j = 0; j < 16; ++j){
    A2[j] = -__expf(Al[d*16 + j]) * 1.44269504f;
    Pp[j] = 1.f; Ss[j] = 0.f;
  }
  int li0 = dir ? ((3-wv)*64 + 63) : (wv*64);
  int stp = dir ? -1 : 1;
  #pragma unroll 2
  for (int i = 0; i < CHL; ++i){
    int li = li0 + stp*i;
    float4 dl = sDlt[li];
    float dtv = softplus_fast(fmaf(wd.x,dl.x, fmaf(wd.y,dl.y,
                              fmaf(wd.z,dl.z, fmaf(wd.w,dl.w, bd)))));
    float uv = b2f(sU[li*64 + d]);
    float du = dtv * uv;
    float bb[16];
    b4fu(*(const uint2*)&sB[li*16     ], bb);
    b4fu(*(const uint2*)&sB[li*16 + 4 ], bb+4);
    b4fu(*(const uint2*)&sB[li*16 + 8 ], bb+8);
    b4fu(*(const uint2*)&sB[li*16 + 12], bb+12);
    #pragma unroll
    for (int j = 0; j < 16; ++j){
      float a = exp2f(dtv*A2[j]);
      Pp[j] *= a;
      Ss[j] = fmaf(a, Ss[j], du*bb[j]);
    }
  }
  size_t pidx = (((size_t)(b*2+dir)*NCH + c)*64 + d)*16;
  #pragma unroll
  for (int k = 0; k < 4; ++k){
    ((float4*)(P + pidx))[k] = make_float4(Pp[4*k],Pp[4*k+1],Pp[4*k+2],Pp[4*k+3]);
    ((float4*)(S + pidx))[k] = make_float4(Ss[4*k],Ss[4*k+1],Ss[4*k+2],Ss[4*k+3]);
  }
}

// ================================================================ K4b: Kogge-Stone carry scan
__global__ __launch_bounds__(256) void k4b_ks(float* __restrict__ P,
                                              const float* __restrict__ S)
{
  __shared__ float Pl[256*18], Sl[256*18];
  int c = threadIdx.x;
  int d = blockIdx.x & 63, bd = blockIdx.x >> 6;
  size_t idx = (((size_t)bd*NCH + c)*64 + d)*16;
  float p[16], s[16];
  #pragma unroll
  for (int k = 0; k < 4; k++){
    float4 pv = ((const float4*)(P + idx))[k];
    float4 sv = ((const float4*)(S + idx))[k];
    p[4*k]=pv.x; p[4*k+1]=pv.y; p[4*k+2]=pv.z; p[4*k+3]=pv.w;
    s[4*k]=sv.x; s[4*k+1]=sv.y; s[4*k+2]=sv.z; s[4*k+3]=sv.w;
  }
  #pragma unroll
  for (int j = 0; j < 8; j++){
    *(float2*)&Pl[c*18 + 2*j] = make_float2(p[2*j], p[2*j+1]);
    *(float2*)&Sl[c*18 + 2*j] = make_float2(s[2*j], s[2*j+1]);
  }
  for (int step = 1; step < NCH; step <<= 1){
    __syncthreads();
    float pp[16], ss[16];
    bool act = (c >= step);
    if (act){
      #pragma unroll
      for (int j = 0; j < 8; j++){
        float2 tp = *(const float2*)&Pl[(c-step)*18 + 2*j];
        float2 ts = *(const float2*)&Sl[(c-step)*18 + 2*j];
        pp[2*j]=tp.x; pp[2*j+1]=tp.y; ss[2*j]=ts.x; ss[2*j+1]=ts.y;
      }
    }
    __syncthreads();
    if (act){
      #pragma unroll
      for (int n = 0; n < 16; n++){
        s[n] = fmaf(p[n], ss[n], s[n]);
        p[n] *= pp[n];
      }
      #pragma unroll
      for (int j = 0; j < 8; j++){
        *(float2*)&Pl[c*18 + 2*j] = make_float2(p[2*j], p[2*j+1]);
        *(float2*)&Sl[c*18 + 2*j] = make_float2(s[2*j], s[2*j+1]);
      }
    }
  }
  __syncthreads();
  float ho[16];
  if (c == 0){
    #pragma unroll
    for (int n = 0; n < 16; n++) ho[n] = 0.f;
  } else {
    #pragma unroll
    for (int j = 0; j < 8; j++){
      float2 ts = *(const float2*)&Sl[(c-1)*18 + 2*j];
      ho[2*j]=ts.x; ho[2*j+1]=ts.y;
    }
  }
  #pragma unroll
  for (int k = 0; k < 4; k++)
    ((float4*)(P + idx))[k] = make_float4(ho[4*k], ho[4*k+1], ho[4*k+2], ho[4*k+3]);
}

// ================================================================ K4c: scan pass B
// same full-d mapping: wave per chunk, lane = d, 16 states; y-dot in-thread,
// zero cross-lane ops; y stored direct (coalesced 256B/wave/step).
__global__ __launch_bounds__(256) void k4c_scanB(
    const float* __restrict__ dltf, const float* __restrict__ dltr,
    const float* __restrict__ dtwf, const float* __restrict__ dtbf,
    const float* __restrict__ dtwr, const float* __restrict__ dtbr,
    const float* __restrict__ uf,  const float* __restrict__ ur,
    const unsigned short* __restrict__ Bf, const unsigned short* __restrict__ Br,
    const unsigned short* __restrict__ Cf, const unsigned short* __restrict__ Cr,
    const float* __restrict__ Alf, const float* __restrict__ Alr,
    const float* __restrict__ Dvf, const float* __restrict__ Dvr,
    const float* __restrict__ Hpre, float* __restrict__ yf, float* __restrict__ yr)
{
  __shared__ unsigned short sU[256*64];   // 32 KB
  __shared__ unsigned short sB[256*16];   // 8 KB
  __shared__ unsigned short sC[256*16];   // 8 KB
  __shared__ float4 sDlt[256];            // 4 KB
  int tid = threadIdx.x;
  int bx = blockIdx.x;
  int w = bx & 63, dir = (bx >> 6) & 1, b = bx >> 7;
  const float* dlt = dir ? dltr : dltf;
  const float* u   = dir ? ur  : uf;
  const unsigned short* Bm = dir ? Br : Bf;
  const unsigned short* Cm = dir ? Cr : Cf;
  const float* Al  = dir ? Alr : Alf;
  const float* dtw = dir ? dtwr : dtwf;
  const float* dtb = dir ? dtbr : dtbf;
  float Dd;
  float* y = dir ? yr : yf;
  size_t t0 = (size_t)b*SEQL + (dir ? (SEQL - (size_t)(w+1)*256) : (size_t)w*256);
  {
    const float4* gu = (const float4*)(u + t0*64);
    #pragma unroll
    for (int i = 0; i < 16; ++i){
      float4 v = gu[tid + i*256];
      uint2 pk;
      pk.x = (unsigned)f2b(v.x) | ((unsigned)f2b(v.y) << 16);
      pk.y = (unsigned)f2b(v.z) | ((unsigned)f2b(v.w) << 16);
      ((uint2*)sU)[tid + i*256] = pk;
    }
    #pragma unroll
    for (int i = 0; i < 4; ++i){
      ((uint2*)sB)[tid + i*256] = ((const uint2*)(Bm + t0*16))[tid + i*256];
      ((uint2*)sC)[tid + i*256] = ((const uint2*)(Cm + t0*16))[tid + i*256];
    }
    sDlt[tid] = ((const float4*)(dlt + t0*4))[tid];
  }
  __syncthreads();
  int lane = tid & 63, wv = tid >> 6;
  int d = lane;
  int c = w*4 + wv;
  Dd = (dir ? Dvr : Dvf)[d];
  float4 wd = ((const float4*)dtw)[d];
  float bd = dtb[d];
  float A2[16], h[16];
  #pragma unroll
  for (int j = 0; j < 16; ++j)
    A2[j] = -__expf(Al[d*16 + j]) * 1.44269504f;
  size_t pidx = (((size_t)(b*2+dir)*NCH + c)*64 + d)*16;
  #pragma unroll
  for (int k = 0; k < 4; ++k){
    float4 hv = ((const float4*)(Hpre + pidx))[k];
    h[4*k]=hv.x; h[4*k+1]=hv.y; h[4*k+2]=hv.z; h[4*k+3]=hv.w;
  }
  int li0 = dir ? ((3-wv)*64 + 63) : (wv*64);
  int stp = dir ? -1 : 1;
  #pragma unroll 2
  for (int i = 0; i < CHL; ++i){
    int li = li0 + stp*i;
    float4 dl = sDlt[li];
    float dtv = softplus_fast(fmaf(wd.x,dl.x, fmaf(wd.y,dl.y,
                              fmaf(wd.z,dl.z, fmaf(wd.w,dl.w, bd)))));
    float uv = b2f(sU[li*64 + d]);
    float du = dtv * uv;
    float bb[16], cc[16];
    b4fu(*(const uint2*)&sB[li*16     ], bb);
    b4fu(*(const uint2*)&sB[li*16 + 4 ], bb+4);
    b4fu(*(const uint2*)&sB[li*16 + 8 ], bb+8);
    b4fu(*(const uint2*)&sB[li*16 + 12], bb+12);
    b4fu(*(const uint2*)&sC[li*16     ], cc);
    b4fu(*(const uint2*)&sC[li*16 + 4 ], cc+4);
    b4fu(*(const uint2*)&sC[li*16 + 8 ], cc+8);
    b4fu(*(const uint2*)&sC[li*16 + 12], cc+12);
    float yv = uv * Dd;
    #pragma unroll
    for (int j = 0; j < 16; ++j){
      float a = exp2f(dtv*A2[j]);
      h[j] = fmaf(a, h[j], du*bb[j]);
      yv = fmaf(h[j], cc[j], yv);
    }
    y[(t0 + li)*64 + d] = yv;
  }
}

// ================================================================ G3: epilogue
__global__ __launch_bounds__(256) void g3_post(
    const float* __restrict__ yf, const float* __restrict__ yr,
    const unsigned short* __restrict__ zb, const unsigned short* __restrict__ zeb,
    const float* __restrict__ wg, const float* __restrict__ x0n,
    const float* __restrict__ in0,
    const float* __restrict__ mnw, const float* __restrict__ opw,
    const float* __restrict__ pnw, const float* __restrict__ pnb,
    float* __restrict__ out)
{
  __shared__ __align__(16) short Wl[64*72];
  __shared__ __align__(16) short Al[64*72];
  __shared__ float Dbuf[64*66];
  int tid = threadIdx.x;
  int t0 = blockIdx.x * 64;
  for (int sseg = tid; sseg < 64*8; sseg += 256){
    int row = sseg >> 3, sg = sseg & 7;
    const float* src = opw + (size_t)row*64 + sg*8;
    float4 f0 = ((const float4*)src)[0];
    float4 f1 = ((const float4*)src)[1];
    short8 v;
    v[0]=(short)f2b(f0.x); v[1]=(short)f2b(f0.y); v[2]=(short)f2b(f0.z); v[3]=(short)f2b(f0.w);
    v[4]=(short)f2b(f1.x); v[5]=(short)f2b(f1.y); v[6]=(short)f2b(f1.z); v[7]=(short)f2b(f1.w);
    *(short8*)&Wl[row*72 + sg*8] = v;
  }
  {
    int tl = tid >> 2, p = tid & 3;
    size_t g = (size_t)(t0 + tl)*64 + p*16;
    float4 yf4[4], yr4[4];
    #pragma unroll
    for (int i = 0; i < 4; i++){
      yf4[i] = ((const float4*)(yf + g))[i];
      yr4[i] = ((const float4*)(yr + g))[i];
    }
    short8 z8a  = *(const short8*)(zb + g);
    short8 z8b  = *(const short8*)(zb + g + 8);
    short8 ze8a = *(const short8*)(zeb + g);
    short8 ze8b = *(const short8*)(zeb + g + 8);
    float vy[16]; float ss = 0.f;
    #pragma unroll
    for (int i = 0; i < 16; i++){
      float yfv = ((const float*)yf4)[i];
      float yrv = ((const float*)yr4)[i];
      float zv  = b2f((unsigned short)(i < 8 ? z8a[i] : z8b[i-8]));
      float zev = b2f((unsigned short)(i < 8 ? ze8a[i] : ze8b[i-8]));
      float v = 0.5f*(yfv*siluf(zv) + yrv*siluf(zev));
      vy[i] = v; ss += v*v;
    }
    ss += __shfl_xor(ss, 1, 64);
    ss += __shfl_xor(ss, 2, 64);
    float rms = rsqrtf(ss*(1.f/64.f) + 1e-5f);
    #pragma unroll
    for (int i = 0; i < 16; i++){
      float w = mnw[p*16 + i];
      Al[tl*72 + p*16 + i] = (short)f2b(vy[i]*rms*w);
    }
  }
  __syncthreads();
  int lane = tid & 63, wv = tid >> 6;
  int n = lane & 15, q = lane >> 4;
  {
    short8 a0 = *(const short8*)&Al[(wv*16 + n)*72 + q*8];
    short8 a1 = *(const short8*)&Al[(wv*16 + n)*72 + 32 + q*8];
    #pragma unroll
    for (int o = 0; o < 4; ++o){
      short8 b0 = *(const short8*)&Wl[(o*16 + n)*72 + q*8];
      short8 b1 = *(const short8*)&Wl[(o*16 + n)*72 + 32 + q*8];
      f32x4 c = {0.f, 0.f, 0.f, 0.f};
      c = __builtin_amdgcn_mfma_f32_16x16x32_bf16(a0, b0, c, 0, 0, 0);
      c = __builtin_amdgcn_mfma_f32_16x16x32_bf16(a1, b1, c, 0, 0, 0);
      #pragma unroll
      for (int r = 0; r < 4; ++r)
        Dbuf[(wv*16 + q*4 + r)*66 + o*16 + n] = c[r];
    }
  }
  __syncthreads();
  float gpw = pnw[lane], gpb = pnb[lane];
  float s1, s2;
  for (int i = 0; i < 16; ++i){
    int tl = wv*16 + i;
    size_t off = (size_t)(t0 + tl)*64 + lane;
    float v = Dbuf[tl*66 + lane];
    s1 = v; s2 = v*v;
    #pragma unroll
    for (int o2 = 32; o2 > 0; o2 >>= 1){ s1 += __shfl_xor(s1,o2,64); s2 += __shfl_xor(s2,o2,64); }
    float m = s1*(1.f/64.f);
    float qv = s2*(1.f/64.f) - m*m;
    float o = (v-m)*rsqrtf(qv+1e-5f)*gpw + gpb;
    o = nan2num(o, 0.f, 1.f, -1.f);
    float w = wg[off];
    float skip = nan2num(in0[off], 0.f, 1.f, -1.f);
    out[off] = fmaf(o, w, fmaf(x0n[off], 1.f - w, skip));
  }
}

// ================================================================ launcher
extern "C" void kernel_launch(void* const* d_in, const int* in_sizes, int n_in,
                              void* d_out, int out_size, void* d_ws, size_t ws_size,
                              hipStream_t stream)
{
  (void)in_sizes; (void)n_in; (void)out_size; (void)ws_size;
  const float* in0  = (const float*)d_in[0];
  const float* in1  = (const float*)d_in[1];
  const float* n0w  = (const float*)d_in[2];
  const float* n0b  = (const float*)d_in[3];
  const float* n1w  = (const float*)d_in[4];
  const float* n1b  = (const float*)d_in[5];
  const float* cww  = (const float*)d_in[6];
  const float* cwb  = (const float*)d_in[7];
  const float* cwnw = (const float*)d_in[8];
  const float* cwnb = (const float*)d_in[9];
  const float* ipw  = (const float*)d_in[10];
  const float* ipew = (const float*)d_in[11];
  const float* cwf  = (const float*)d_in[12];
  const float* cbf  = (const float*)d_in[13];
  const float* xpwf = (const float*)d_in[14];
  const float* dtwf = (const float*)d_in[15];
  const float* dtbf = (const float*)d_in[16];
  const float* Alf  = (const float*)d_in[17];
  const float* Dvf  = (const float*)d_in[18];
  const float* cwr  = (const float*)d_in[19];
  const float* cbr  = (const float*)d_in[20];
  const float* xpwr = (const float*)d_in[21];
  const float* dtwr = (const float*)d_in[22];
  const float* dtbr = (const float*)d_in[23];
  const float* Alr  = (const float*)d_in[24];
  const float* Dvr  = (const float*)d_in[25];
  const float* mnw  = (const float*)d_in[26];
  const float* opw  = (const float*)d_in[27];
  const float* pnw  = (const float*)d_in[28];
  const float* pnb  = (const float*)d_in[29];

  float* ws  = (float*)d_ws;
  float* x0n = ws + 0*EL;
  float* xa  = ws + 1*EL;   // conv input fwd; reused as yf
  float* xe  = ws + 2*EL;   // conv input rev; reused as yr
  float* uf  = ws + 3*EL;
  float* ur  = ws + 4*EL;
  float* wg  = ws + 5*EL;
  unsigned short* Bf = (unsigned short*)(ws + 6*EL);   // TOK*16 ushorts each
  unsigned short* Cf = Bf + (size_t)TOK*16;
  unsigned short* Br = Cf + (size_t)TOK*16;
  unsigned short* Cr = Br + (size_t)TOK*16;
  float* P   = ws + 7*EL;              // 2*TOK*16 floats = EL/2
  float* S   = P + 2*(size_t)TOK*16;   // EL/2
  unsigned short* zb  = (unsigned short*)(ws + 8*EL);
  unsigned short* zeb = zb + EL;
  float* dltf = ws + 9*EL;             // TOK*4 each
  float* dltr = dltf + (size_t)TOK*4;
  float* yfp = xa;
  float* yrp = xe;

  mega1<<<512, 256, 0, stream>>>(in0, in1, n0w, n0b, n1w, n1b, cww, cwb,
                                 cwnw, cwnb, ipw, ipew,
                                 x0n, wg, xa, xe, zb, zeb);
  g2_convproj<<<512, 256, 0, stream>>>(xa, xe, cwf, cbf, cwr, cbr,
                                       xpwf, xpwr,
                                       uf, ur, dltf, dltr, Bf, Cf, Br, Cr);
  k4a_scanA<<<512, 256, 0, stream>>>(dltf, dltr, dtwf, dtbf, dtwr, dtbr,
                                     uf, ur, Bf, Br, Alf, Alr, P, S);
  k4b_ks<<<512, 256, 0, stream>>>(P, S);
  k4c_scanB<<<512, 256, 0, stream>>>(dltf, dltr, dtwf, dtbf, dtwr, dtbr,
                                     uf, ur, Bf, Br, Cf, Cr,
                                     Alf, Alr, Dvf, Dvr, P, yfp, yrp);
  g3_post<<<1024, 256, 0, stream>>>(yfp, yrp, zb, zeb, wg, x0n, in0,
                                    mnw, opw, pnw, pnb, (float*)d_out);
}